// Round 1
// baseline (535.269 us; speedup 1.0000x reference)
//
#include <hip/hip_runtime.h>
#include <hip/hip_bf16.h>
#include <math.h>

#define B_N   1024
#define M_N   200000
#define DIN   256
#define DIMN  128
#define DOUT  10
#define EPS_F 1e-7f
#define M_PAD 200064   // 1563 * 128
#define NBY   1563     // M_PAD / 128
#define CTILES 8       // col-tiles per fused block

typedef __bf16 bf16_t;
typedef __bf16 bf16x8 __attribute__((ext_vector_type(8)));
typedef float  f32x4  __attribute__((ext_vector_type(4)));

// ---------- small utility kernels ----------

__global__ void cvt_w_kernel(const float* __restrict__ W, bf16_t* __restrict__ Wb){
    int i = blockIdx.x*256 + threadIdx.x;
    if (i < DIMN*DIN) Wb[i] = (bf16_t)W[i];
}

// hist[c*16] line-padded
__global__ void hist_kernel(const int* __restrict__ cy, int* __restrict__ hist){
    __shared__ int h[DOUT];
    if (threadIdx.x < DOUT) h[threadIdx.x] = 0;
    __syncthreads();
    for (int i = blockIdx.x*blockDim.x + threadIdx.x; i < M_N; i += gridDim.x*blockDim.x)
        atomicAdd(&h[cy[i]], 1);
    __syncthreads();
    if (threadIdx.x < DOUT) atomicAdd(&hist[threadIdx.x*16], h[threadIdx.x]);
}

__global__ void prefix_kernel(const int* __restrict__ hist, int* __restrict__ cs){
    if (threadIdx.x == 0 && blockIdx.x == 0){
        int acc = 0;
        for (int c = 0; c < DOUT; ++c){ cs[c] = acc; acc += hist[c*16]; }
        cs[DOUT] = acc;   // == M_N
    }
}

// ---------- encoder: out[pos[m]] = bf16(src[m] @ Wb^T), onorm[pos[m]] = ||row||^2 ----------

__global__ __launch_bounds__(256) void encode_kernel(
    const float* __restrict__ src, const bf16_t* __restrict__ Wb,
    bf16_t* __restrict__ out, float* __restrict__ onorm, int N,
    const int* __restrict__ ycls, int* __restrict__ counters,
    const int* __restrict__ cs)
{
    __shared__ bf16_t As[128][136];   // 34 KB
    __shared__ int   posL[128];
    __shared__ float nbuf[128][2];
    __shared__ int   cntL[DOUT], baseL[DOUT];
    const int tid = threadIdx.x;
    const int r0  = blockIdx.x*128;

    int myc = -1, myrank = 0;
    if (ycls != nullptr){
        if (tid < DOUT) cntL[tid] = 0;
        __syncthreads();
        if (tid < 128 && r0 + tid < N){
            myc = ycls[r0 + tid];
            myrank = atomicAdd(&cntL[myc], 1);      // LDS atomic: block-local rank
        }
        __syncthreads();
        if (tid < DOUT && cntL[tid] > 0)
            baseL[tid] = atomicAdd(&counters[tid*16], cntL[tid]);  // padded lines
        __syncthreads();
    }
    if (tid < 128)
        posL[tid] = (myc >= 0) ? (cs[myc] + baseL[myc] + myrank) : (r0 + tid);

    const int lane = tid & 63, wid = tid >> 6;
    const int wr = wid >> 1, wc = wid & 1;
    const int l15 = lane & 15, quad = lane >> 4;
    const int cbase = wc*64;

    f32x4 acc[4][4] = {};
    #pragma unroll
    for (int kh = 0; kh < 2; ++kh){
        __syncthreads();
        #pragma unroll
        for (int i = 0; i < 8; ++i){
            int idx = i*256 + tid;        // 2048 chunks of 8 floats
            int row = idx >> 4;
            int col = (idx & 15)*8;
            int rr  = r0 + row; if (rr > N-1) rr = N-1;
            const float4* p4 = (const float4*)(src + (size_t)rr*DIN + kh*128 + col);
            float4 f0 = p4[0], f1 = p4[1];
            bf16x8 v;
            v[0]=(bf16_t)f0.x; v[1]=(bf16_t)f0.y; v[2]=(bf16_t)f0.z; v[3]=(bf16_t)f0.w;
            v[4]=(bf16_t)f1.x; v[5]=(bf16_t)f1.y; v[6]=(bf16_t)f1.z; v[7]=(bf16_t)f1.w;
            *(bf16x8*)&As[row][col] = v;
        }
        __syncthreads();
        #pragma unroll
        for (int ks = 0; ks < 4; ++ks){
            const int k  = ks*32 + quad*8;
            const int kg = kh*128 + k;
            bf16x8 a[4], b[4];
            #pragma unroll
            for (int rt = 0; rt < 4; ++rt)
                a[rt] = *(const bf16x8*)&As[wr*64 + rt*16 + l15][k];
            #pragma unroll
            for (int ct = 0; ct < 4; ++ct)
                b[ct] = *(const bf16x8*)(Wb + (size_t)(cbase + ct*16 + l15)*DIN + kg);
            #pragma unroll
            for (int rt = 0; rt < 4; ++rt)
                #pragma unroll
                for (int ct = 0; ct < 4; ++ct)
                    acc[rt][ct] = __builtin_amdgcn_mfma_f32_16x16x32_bf16(a[rt], b[ct], acc[rt][ct], 0, 0, 0);
        }
    }

    // ||row||^2: per-lane partial over 4 cols, butterfly over 16-lane col group
    float np[4][4];
    #pragma unroll
    for (int rt = 0; rt < 4; ++rt)
        #pragma unroll
        for (int r = 0; r < 4; ++r){
            float s = 0.f;
            #pragma unroll
            for (int ct = 0; ct < 4; ++ct){ float v = acc[rt][ct][r]; s += v*v; }
            np[rt][r] = s;
        }
    #pragma unroll
    for (int m = 1; m < 16; m <<= 1)
        #pragma unroll
        for (int rt = 0; rt < 4; ++rt)
            #pragma unroll
            for (int r = 0; r < 4; ++r)
                np[rt][r] += __shfl_xor(np[rt][r], m, 64);
    if (l15 == 0){
        #pragma unroll
        for (int rt = 0; rt < 4; ++rt)
            #pragma unroll
            for (int r = 0; r < 4; ++r)
                nbuf[wr*64 + rt*16 + quad*4 + r][wc] = np[rt][r];
    }

    // scatter-store bf16 rows (C/D layout: col = l15, row = quad*4 + r)
    #pragma unroll
    for (int rt = 0; rt < 4; ++rt){
        #pragma unroll
        for (int r = 0; r < 4; ++r){
            int rl = wr*64 + rt*16 + quad*4 + r;
            if (r0 + rl < N){
                size_t rowp = (size_t)posL[rl]*DIMN;
                #pragma unroll
                for (int ct = 0; ct < 4; ++ct)
                    out[rowp + cbase + ct*16 + l15] = (bf16_t)acc[rt][ct][r];
            }
        }
    }
    __syncthreads();
    if (tid < 128){
        int rs = r0 + tid;
        if (rs < N) onorm[posL[tid]] = nbuf[tid][0] + nbuf[tid][1];
    }
}

// ---------- fused dist -> exp -> class-segmented row sums ----------
// v2: 512 threads / 8 waves, per-wave 32x64 tile (a[4][2]=32 VGPR, acc[2][4]=32 AGPR
// -> ~110 total regs -> 4 waves/SIMD vs 2 before). Staging via global_load_lds
// (width 16) into two distinct unpadded [128][128] buffers; bank conflicts fixed
// by the both-sides XOR involution: source chunk pre-swizzled j^(col&7), ds_read
// byte addr ^ ((l15&7)<<4). Next tile's loads issued BEFORE current compute ->
// one barrier per tile, HBM latency hidden under ~1500cy of MFMA+epilogue.

__device__ __forceinline__ void gld_lds16(const bf16_t* g, bf16_t* l){
    __builtin_amdgcn_global_load_lds((const __attribute__((address_space(1))) void*)g,
                                     (__attribute__((address_space(3))) void*)l, 16, 0, 0);
}

__device__ __forceinline__ void bfly16(float (&s)[2][4]){
    #pragma unroll
    for (int m = 1; m < 16; m <<= 1)
        #pragma unroll
        for (int rt = 0; rt < 2; ++rt)
            #pragma unroll
            for (int r = 0; r < 4; ++r)
                s[rt][r] += __shfl_xor(s[rt][r], m, 64);
}

__device__ __forceinline__ void flushC(float (&s)[2][4], int c, int rbase,
                                       int quad, int l15, float* __restrict__ accG){
    bfly16(s);
    if (l15 == 0){
        #pragma unroll
        for (int rt = 0; rt < 2; ++rt)
            #pragma unroll
            for (int r = 0; r < 4; ++r)
                atomicAdd(&accG[(size_t)(rbase + rt*16 + quad*4 + r)*16 + c], s[rt][r]);
    }
}

__global__ __launch_bounds__(512, 4) void fused_kernel(
    const bf16_t* __restrict__ hb, const bf16_t* __restrict__ hcb,
    const float* __restrict__ hn, const float* __restrict__ hcn,
    const int* __restrict__ csg, float* __restrict__ accG)
{
    __shared__ bf16_t Bs0[128][128];   // 32 KB, linear (swizzle is in the addressing)
    __shared__ bf16_t Bs1[128][128];   // 32 KB
    const int tid = threadIdx.x;
    const int lane = tid & 63, wid = tid >> 6;          // 8 waves
    const int wr = wid >> 1, wc = wid & 1;              // 4 row-groups x 2 col-groups
    const int l15 = lane & 15, quad = lane >> 4;
    const int rbase = blockIdx.x*128 + wr*32;

    // A fragments: fixed per block, held in registers (32 VGPRs)
    bf16x8 a[4][2];
    #pragma unroll
    for (int ks = 0; ks < 4; ++ks)
        #pragma unroll
        for (int rt = 0; rt < 2; ++rt)
            a[ks][rt] = *(const bf16x8*)(hb + (size_t)(rbase + rt*16 + l15)*DIMN + ks*32 + quad*8);

    float hnv[2][4];
    #pragma unroll
    for (int rt = 0; rt < 2; ++rt)
        #pragma unroll
        for (int r = 0; r < 4; ++r)
            hnv[rt][r] = hn[rbase + rt*16 + quad*4 + r];

    int cseg[DOUT+1];
    #pragma unroll
    for (int i = 0; i <= DOUT; ++i) cseg[i] = __builtin_amdgcn_readfirstlane(csg[i]);

    const int by0 = blockIdx.y*CTILES;
    int nt = NBY - by0; if (nt > CTILES) nt = CTILES;

    float s[2][4] = {};
    int curC = -1;

    auto stage = [&](bf16_t (&Bsb)[128][128], int by){
        const int cb = by*128;
        #pragma unroll
        for (int i = 0; i < 4; ++i){
            int c   = i*512 + tid;          // dest chunk (2048 x 16B covers the tile)
            int col = c >> 4, j = c & 15;
            int cc  = cb + col; if (cc > M_N-1) cc = M_N-1;
            const bf16_t* g = hcb + (size_t)cc*DIMN + ((j ^ (col & 7)) << 3); // pre-swizzled src
            bf16_t* l = &Bsb[0][0] + ((i*512 + (wid << 6)) << 3);             // wave-uniform base
            gld_lds16(g, l);
        }
    };

    auto compute = [&](const bf16_t (&Bsb)[128][128], int by){
        const int cbase0 = by*128;
        f32x4 acc[2][4] = {};
        const char* bsb = (const char*)&Bsb[0][0];
        #pragma unroll
        for (int ks = 0; ks < 4; ++ks){
            bf16x8 b[4];
            #pragma unroll
            for (int ct = 0; ct < 4; ++ct){
                int row = wc*64 + ct*16 + l15;
                int off = (row << 8) + ((((ks << 6) + (quad << 4))) ^ ((l15 & 7) << 4));
                b[ct] = *(const bf16x8*)(bsb + off);
            }
            #pragma unroll
            for (int rt = 0; rt < 2; ++rt)
                #pragma unroll
                for (int ct = 0; ct < 4; ++ct)
                    acc[rt][ct] = __builtin_amdgcn_mfma_f32_16x16x32_bf16(a[ks][rt], b[ct], acc[rt][ct], 0, 0, 0);
        }

        // epilogue: prob = exp(-sqrt(max(|h|^2 + |hc|^2 - 2 dot, 0)))
        float hcnv[4];
        #pragma unroll
        for (int ct = 0; ct < 4; ++ct){
            int cc = cbase0 + wc*64 + ct*16 + l15;
            hcnv[ct] = (cc < M_N) ? hcn[cc] : 1e30f;   // pad: exp(-1e15) == 0
        }
        #pragma unroll
        for (int rt = 0; rt < 2; ++rt)
            #pragma unroll
            for (int ct = 0; ct < 4; ++ct)
                #pragma unroll
                for (int r = 0; r < 4; ++r){
                    float sq = fmaxf(fmaf(-2.0f, acc[rt][ct][r], hnv[rt][r] + hcnv[ct]), 0.0f);
                    acc[rt][ct][r] = __expf(-__builtin_amdgcn_sqrtf(sq));
                }

        // class span of this tile (block-uniform)
        const int lastc = min(cbase0 + 127, M_N - 1);
        int cLo = 0, cHi = 0;
        #pragma unroll
        for (int c = 1; c < DOUT; ++c){
            if (cbase0 >= cseg[c]) cLo = c;
            if (lastc  >= cseg[c]) cHi = c;
        }

        if (cLo == curC && cHi == curC){
            #pragma unroll
            for (int rt = 0; rt < 2; ++rt)
                #pragma unroll
                for (int r = 0; r < 4; ++r){
                    float v0 = acc[rt][0][r] + acc[rt][1][r];
                    float v1 = acc[rt][2][r] + acc[rt][3][r];
                    s[rt][r] += v0 + v1;
                }
        } else {
            if (curC >= 0) flushC(s, curC, rbase, quad, l15, accG);
            #pragma unroll
            for (int rt = 0; rt < 2; ++rt)
                #pragma unroll
                for (int r = 0; r < 4; ++r) s[rt][r] = 0.f;
            for (int c = cLo; c <= cHi; ++c){
                const int s0 = cseg[c], s1 = cseg[c+1];
                float m[2][4];
                #pragma unroll
                for (int rt = 0; rt < 2; ++rt)
                    #pragma unroll
                    for (int r = 0; r < 4; ++r){
                        float v = 0.f;
                        #pragma unroll
                        for (int ct = 0; ct < 4; ++ct){
                            int cc = cbase0 + wc*64 + ct*16 + l15;
                            v += (cc >= s0 && cc < s1) ? acc[rt][ct][r] : 0.f;
                        }
                        m[rt][r] = v;
                    }
                if (c == cHi){
                    #pragma unroll
                    for (int rt = 0; rt < 2; ++rt)
                        #pragma unroll
                        for (int r = 0; r < 4; ++r) s[rt][r] = m[rt][r];
                    curC = cHi;
                } else {
                    flushC(m, c, rbase, quad, l15, accG);
                }
            }
        }
    };

    stage(Bs0, by0);
    __syncthreads();

    #pragma unroll 1
    for (int tp = 0; tp < CTILES/2; ++tp){
        int t0 = tp*2;
        if (t0 >= nt) break;
        if (t0 + 1 < nt) stage(Bs1, by0 + t0 + 1);   // issue next-tile loads first
        compute(Bs0, by0 + t0);
        __syncthreads();                             // drains vmcnt -> Bs1 ready
        int t1 = t0 + 1;
        if (t1 >= nt) break;
        if (t1 + 1 < nt) stage(Bs0, by0 + t1 + 1);
        compute(Bs1, by0 + t1);
        __syncthreads();
    }
    if (curC >= 0) flushC(s, curC, rbase, quad, l15, accG);
}

__global__ void finalize_kernel(const float* __restrict__ accG, float* __restrict__ out){
    int b = blockIdx.x*blockDim.x + threadIdx.x;
    if (b < B_N){
        float v[DOUT]; float den = 0.f;
        #pragma unroll
        for (int c = 0; c < DOUT; ++c){ v[c] = accG[b*16 + c]; den += v[c]; }
        float inv = (den > 0.f) ? 1.0f/den : 0.f;
        #pragma unroll
        for (int c = 0; c < DOUT; ++c) out[b*DOUT + c] = logf(v[c]*inv + EPS_F);
    }
}

// ---------- launch ----------

extern "C" void kernel_launch(void* const* d_in, const int* in_sizes, int n_in,
                              void* d_out, int out_size, void* d_ws, size_t ws_size,
                              hipStream_t stream)
{
    const float* x  = (const float*)d_in[0];
    // d_in[1] = y (unused on eval path)
    const float* cx = (const float*)d_in[2];
    const int*   cy = (const int*)d_in[3];
    const float* W  = (const float*)d_in[4];
    // d_in[5] = b_enc: cancels exactly in ||h - hc||, skipped
    // d_in[6] = is_train (eval path)
    float* out = (float*)d_out;

    char* w = (char*)d_ws;
    size_t off = 0;
    bf16_t* hcb = (bf16_t*)(w + off); off += (size_t)M_PAD*DIMN*2;  // 51,216,384
    bf16_t* hb  = (bf16_t*)(w + off); off += (size_t)B_N*DIMN*2;    //    262,144
    float*  hcn = (float*) (w + off); off += (size_t)M_PAD*4;       //    800,256
    float*  hn  = (float*) (w + off); off += (size_t)B_N*4;         //      4,096
    bf16_t* Wb  = (bf16_t*)(w + off); off += (size_t)DIMN*DIN*2;    //     65,536
    size_t zoff = off;
    float* accG = (float*)(w + off); off += (size_t)B_N*16*4;       //     65,536
    int* hist     = (int*)(w + off); off += 16*DOUT*4;              // line-padded
    int* counters = (int*)(w + off); off += 16*DOUT*4;              // line-padded
    int* csg      = (int*)(w + off); off += 64;
    size_t zsize = off - zoff;

    hipMemsetAsync(w + zoff, 0, zsize, stream);
    cvt_w_kernel<<<dim3((DIMN*DIN + 255)/256), dim3(256), 0, stream>>>(W, Wb);
    hist_kernel<<<dim3(256), dim3(256), 0, stream>>>(cy, hist);
    prefix_kernel<<<dim3(1), dim3(1), 0, stream>>>(hist, csg);
    encode_kernel<<<dim3(M_PAD/128), dim3(256), 0, stream>>>(cx, Wb, hcb, hcn, M_N, cy, counters, csg);
    encode_kernel<<<dim3(B_N/128), dim3(256), 0, stream>>>(x, Wb, hb, hn, B_N, nullptr, nullptr, nullptr);
    fused_kernel<<<dim3(B_N/128, (NBY + CTILES - 1)/CTILES), dim3(512), 0, stream>>>(hb, hcb, hn, hcn, csg, accG);
    finalize_kernel<<<dim3((B_N + 255)/256), dim3(256), 0, stream>>>(accG, out);
}

// Round 2
// 482.402 us; speedup vs baseline: 1.1096x; 1.1096x over previous
//
#include <hip/hip_runtime.h>
#include <hip/hip_bf16.h>
#include <math.h>

#define B_N   1024
#define M_N   200000
#define DIN   256
#define DIMN  128
#define DOUT  10
#define EPS_F 1e-7f
#define M_PAD 200064   // 1563 * 128
#define NBY   1563     // M_PAD / 128
#define CTILES 8       // col-tiles per fused block
#define NGRP  ((NBY + CTILES - 1)/CTILES)   // 196 col-groups
#define YPAD  200                           // 25*8: clean bijective XCD remap

typedef __bf16 bf16_t;
typedef __bf16 bf16x8 __attribute__((ext_vector_type(8)));
typedef float  f32x4  __attribute__((ext_vector_type(4)));

// ---------- small utility kernels ----------

__global__ void cvt_w_kernel(const float* __restrict__ W, bf16_t* __restrict__ Wb){
    int i = blockIdx.x*256 + threadIdx.x;
    if (i < DIMN*DIN) Wb[i] = (bf16_t)W[i];
}

// hist[c*16] line-padded
__global__ void hist_kernel(const int* __restrict__ cy, int* __restrict__ hist){
    __shared__ int h[DOUT];
    if (threadIdx.x < DOUT) h[threadIdx.x] = 0;
    __syncthreads();
    for (int i = blockIdx.x*blockDim.x + threadIdx.x; i < M_N; i += gridDim.x*blockDim.x)
        atomicAdd(&h[cy[i]], 1);
    __syncthreads();
    if (threadIdx.x < DOUT) atomicAdd(&hist[threadIdx.x*16], h[threadIdx.x]);
}

__global__ void prefix_kernel(const int* __restrict__ hist, int* __restrict__ cs){
    if (threadIdx.x == 0 && blockIdx.x == 0){
        int acc = 0;
        for (int c = 0; c < DOUT; ++c){ cs[c] = acc; acc += hist[c*16]; }
        cs[DOUT] = acc;   // == M_N
    }
}

// ---------- encoder: out[pos[m]] = bf16(src[m] @ Wb^T), onorm[pos[m]] = ||row||^2 ----------
// v3: (a) Wb fragments hoisted to registers before the K loop (were global loads
// chained inside the MFMA loop); (b) C-write via LDS staging + coalesced 16B/lane
// row bursts (was 64 scattered 2B stores/thread).

__global__ __launch_bounds__(256) void encode_kernel(
    const float* __restrict__ src, const bf16_t* __restrict__ Wb,
    bf16_t* __restrict__ out, float* __restrict__ onorm, int N,
    const int* __restrict__ ycls, int* __restrict__ counters,
    const int* __restrict__ cs)
{
    __shared__ bf16_t As[128][136];   // 34 KB (staging in, then C-tile out)
    __shared__ int   posL[128];
    __shared__ float nbuf[128][2];
    __shared__ int   cntL[DOUT], baseL[DOUT];
    const int tid = threadIdx.x;
    const int r0  = blockIdx.x*128;

    int myc = -1, myrank = 0;
    if (ycls != nullptr){
        if (tid < DOUT) cntL[tid] = 0;
        __syncthreads();
        if (tid < 128 && r0 + tid < N){
            myc = ycls[r0 + tid];
            myrank = atomicAdd(&cntL[myc], 1);      // LDS atomic: block-local rank
        }
        __syncthreads();
        if (tid < DOUT && cntL[tid] > 0)
            baseL[tid] = atomicAdd(&counters[tid*16], cntL[tid]);  // padded lines
        __syncthreads();
    }
    if (tid < 128)
        posL[tid] = (myc >= 0) ? (cs[myc] + baseL[myc] + myrank) : (r0 + tid);

    const int lane = tid & 63, wid = tid >> 6;
    const int wr = wid >> 1, wc = wid & 1;
    const int l15 = lane & 15, quad = lane >> 4;
    const int cbase = wc*64;

    // hoist all 8 B fragments (Wb is L2-resident, 64KB)
    bf16x8 ball[2][4];
    #pragma unroll
    for (int kh = 0; kh < 2; ++kh)
        #pragma unroll
        for (int ks = 0; ks < 4; ++ks){
            // NOTE: this lane's 4 ct-fragments share (kh,ks); load the ct=0..3 set lazily below
            ball[kh][ks] = *(const bf16x8*)(Wb + (size_t)(cbase + 0*16 + l15)*DIN + kh*128 + ks*32 + quad*8);
        }
    // remaining ct=1..3 fragments: keep as registers too (24 more bf16x8 = 96 VGPR is too
    // much; instead hold per-ks b[4] loaded once per (kh,ks) but issued before the A reads)

    f32x4 acc[4][4] = {};
    #pragma unroll
    for (int kh = 0; kh < 2; ++kh){
        __syncthreads();
        #pragma unroll
        for (int i = 0; i < 8; ++i){
            int idx = i*256 + tid;        // 2048 chunks of 8 floats
            int row = idx >> 4;
            int col = (idx & 15)*8;
            int rr  = r0 + row; if (rr > N-1) rr = N-1;
            const float4* p4 = (const float4*)(src + (size_t)rr*DIN + kh*128 + col);
            float4 f0 = p4[0], f1 = p4[1];
            bf16x8 v;
            v[0]=(bf16_t)f0.x; v[1]=(bf16_t)f0.y; v[2]=(bf16_t)f0.z; v[3]=(bf16_t)f0.w;
            v[4]=(bf16_t)f1.x; v[5]=(bf16_t)f1.y; v[6]=(bf16_t)f1.z; v[7]=(bf16_t)f1.w;
            *(bf16x8*)&As[row][col] = v;
        }
        __syncthreads();
        #pragma unroll
        for (int ks = 0; ks < 4; ++ks){
            const int k  = ks*32 + quad*8;
            const int kg = kh*128 + k;
            bf16x8 a[4], b[4];
            b[0] = ball[kh][ks];
            #pragma unroll
            for (int ct = 1; ct < 4; ++ct)
                b[ct] = *(const bf16x8*)(Wb + (size_t)(cbase + ct*16 + l15)*DIN + kg);
            #pragma unroll
            for (int rt = 0; rt < 4; ++rt)
                a[rt] = *(const bf16x8*)&As[wr*64 + rt*16 + l15][k];
            #pragma unroll
            for (int rt = 0; rt < 4; ++rt)
                #pragma unroll
                for (int ct = 0; ct < 4; ++ct)
                    acc[rt][ct] = __builtin_amdgcn_mfma_f32_16x16x32_bf16(a[rt], b[ct], acc[rt][ct], 0, 0, 0);
        }
    }

    // ||row||^2: per-lane partial over 4 cols, butterfly over 16-lane col group
    float np[4][4];
    #pragma unroll
    for (int rt = 0; rt < 4; ++rt)
        #pragma unroll
        for (int r = 0; r < 4; ++r){
            float s = 0.f;
            #pragma unroll
            for (int ct = 0; ct < 4; ++ct){ float v = acc[rt][ct][r]; s += v*v; }
            np[rt][r] = s;
        }
    #pragma unroll
    for (int m = 1; m < 16; m <<= 1)
        #pragma unroll
        for (int rt = 0; rt < 4; ++rt)
            #pragma unroll
            for (int r = 0; r < 4; ++r)
                np[rt][r] += __shfl_xor(np[rt][r], m, 64);
    if (l15 == 0){
        #pragma unroll
        for (int rt = 0; rt < 4; ++rt)
            #pragma unroll
            for (int r = 0; r < 4; ++r)
                nbuf[wr*64 + rt*16 + quad*4 + r][wc] = np[rt][r];
    }

    __syncthreads();   // As reads + nbuf writes complete; safe to overwrite As

    // stage C-tile into LDS (C/D layout: col = l15, row = quad*4 + r)
    #pragma unroll
    for (int rt = 0; rt < 4; ++rt)
        #pragma unroll
        for (int r = 0; r < 4; ++r){
            int rl = wr*64 + rt*16 + quad*4 + r;
            #pragma unroll
            for (int ct = 0; ct < 4; ++ct)
                As[rl][cbase + ct*16 + l15] = (bf16_t)acc[rt][ct][r];
        }
    __syncthreads();

    // coalesced writeout: each row = 256B written by 16 lanes x 16B
    {
        const int rsub = tid >> 4;       // 0..15
        const int cpos = (tid & 15)*8;   // bf16 col
        #pragma unroll
        for (int p = 0; p < 8; ++p){
            int rl = p*16 + rsub;
            size_t rowp = (size_t)posL[rl]*DIMN;
            *(bf16x8*)(out + rowp + cpos) = *(const bf16x8*)&As[rl][cpos];
        }
    }
    if (tid < 128){
        int rs = r0 + tid;
        if (rs < N) onorm[posL[tid]] = nbuf[tid][0] + nbuf[tid][1];
    }
}

// ---------- fused dist -> exp -> class-segmented row sums ----------
// v3: XCD-aware bijective grid remap. HW assigns XCD = lin%8; decode lin so each
// XCD sweeps all 8 row-blocks over ONE col-group before advancing -> each hcb
// byte enters an XCD's L2 once (working set 8 groups x 256KB = 2MB < 4MB L2).
// v2 structure kept: 512 thr / 8 waves, 32x64 wave tile, global_load_lds staging
// with both-sides XOR swizzle, stage-before-compute pipeline.

__device__ __forceinline__ void gld_lds16(const bf16_t* g, bf16_t* l){
    __builtin_amdgcn_global_load_lds((const __attribute__((address_space(1))) void*)g,
                                     (__attribute__((address_space(3))) void*)l, 16, 0, 0);
}

__device__ __forceinline__ void bfly16(float (&s)[2][4]){
    #pragma unroll
    for (int m = 1; m < 16; m <<= 1)
        #pragma unroll
        for (int rt = 0; rt < 2; ++rt)
            #pragma unroll
            for (int r = 0; r < 4; ++r)
                s[rt][r] += __shfl_xor(s[rt][r], m, 64);
}

__device__ __forceinline__ void flushC(float (&s)[2][4], int c, int rbase,
                                       int quad, int l15, float* __restrict__ accG){
    bfly16(s);
    if (l15 == 0){
        #pragma unroll
        for (int rt = 0; rt < 2; ++rt)
            #pragma unroll
            for (int r = 0; r < 4; ++r)
                atomicAdd(&accG[(size_t)(rbase + rt*16 + quad*4 + r)*16 + c], s[rt][r]);
    }
}

__global__ __launch_bounds__(512, 4) void fused_kernel(
    const bf16_t* __restrict__ hb, const bf16_t* __restrict__ hcb,
    const float* __restrict__ hn, const float* __restrict__ hcn,
    const int* __restrict__ csg, float* __restrict__ accG)
{
    // ---- XCD-aware remap (bijective): lin = bx + 8*by; XCD = lin&7 ----
    const int lin = blockIdx.y*8 + blockIdx.x;
    const int i8  = lin & 7;         // XCD id
    const int t   = lin >> 3;        // 0..199
    const int q   = t >> 3;          // 0..24
    const int r8  = t & 7;
    const int bx  = r8;              // row-block 0..7 (swept consecutively per XCD)
    const int yg  = q*8 + i8;        // col-group, pinned to this XCD
    if (yg >= NGRP) return;          // 32 pad blocks exit (uniform per block)

    __shared__ bf16_t Bs0[128][128];   // 32 KB, linear (swizzle is in the addressing)
    __shared__ bf16_t Bs1[128][128];   // 32 KB
    const int tid = threadIdx.x;
    const int lane = tid & 63, wid = tid >> 6;          // 8 waves
    const int wr = wid >> 1, wc = wid & 1;              // 4 row-groups x 2 col-groups
    const int l15 = lane & 15, quad = lane >> 4;
    const int rbase = bx*128 + wr*32;

    // A fragments: fixed per block, held in registers (32 VGPRs)
    bf16x8 a[4][2];
    #pragma unroll
    for (int ks = 0; ks < 4; ++ks)
        #pragma unroll
        for (int rt = 0; rt < 2; ++rt)
            a[ks][rt] = *(const bf16x8*)(hb + (size_t)(rbase + rt*16 + l15)*DIMN + ks*32 + quad*8);

    float hnv[2][4];
    #pragma unroll
    for (int rt = 0; rt < 2; ++rt)
        #pragma unroll
        for (int r = 0; r < 4; ++r)
            hnv[rt][r] = hn[rbase + rt*16 + quad*4 + r];

    int cseg[DOUT+1];
    #pragma unroll
    for (int i = 0; i <= DOUT; ++i) cseg[i] = __builtin_amdgcn_readfirstlane(csg[i]);

    const int by0 = yg*CTILES;
    int nt = NBY - by0; if (nt > CTILES) nt = CTILES;

    float s[2][4] = {};
    int curC = -1;

    auto stage = [&](bf16_t (&Bsb)[128][128], int by){
        const int cb = by*128;
        #pragma unroll
        for (int i = 0; i < 4; ++i){
            int c   = i*512 + tid;          // dest chunk (2048 x 16B covers the tile)
            int col = c >> 4, j = c & 15;
            int cc  = cb + col; if (cc > M_N-1) cc = M_N-1;
            const bf16_t* g = hcb + (size_t)cc*DIMN + ((j ^ (col & 7)) << 3); // pre-swizzled src
            bf16_t* l = &Bsb[0][0] + ((i*512 + (wid << 6)) << 3);             // wave-uniform base
            gld_lds16(g, l);
        }
    };

    auto compute = [&](const bf16_t (&Bsb)[128][128], int by){
        const int cbase0 = by*128;
        f32x4 acc[2][4] = {};
        const char* bsb = (const char*)&Bsb[0][0];
        #pragma unroll
        for (int ks = 0; ks < 4; ++ks){
            bf16x8 b[4];
            #pragma unroll
            for (int ct = 0; ct < 4; ++ct){
                int row = wc*64 + ct*16 + l15;
                int off = (row << 8) + ((((ks << 6) + (quad << 4))) ^ ((l15 & 7) << 4));
                b[ct] = *(const bf16x8*)(bsb + off);
            }
            #pragma unroll
            for (int rt = 0; rt < 2; ++rt)
                #pragma unroll
                for (int ct = 0; ct < 4; ++ct)
                    acc[rt][ct] = __builtin_amdgcn_mfma_f32_16x16x32_bf16(a[ks][rt], b[ct], acc[rt][ct], 0, 0, 0);
        }

        // epilogue: prob = exp(-sqrt(max(|h|^2 + |hc|^2 - 2 dot, 0)))
        float hcnv[4];
        #pragma unroll
        for (int ct = 0; ct < 4; ++ct){
            int cc = cbase0 + wc*64 + ct*16 + l15;
            hcnv[ct] = (cc < M_N) ? hcn[cc] : 1e30f;   // pad: exp(-1e15) == 0
        }
        #pragma unroll
        for (int rt = 0; rt < 2; ++rt)
            #pragma unroll
            for (int ct = 0; ct < 4; ++ct)
                #pragma unroll
                for (int r = 0; r < 4; ++r){
                    float sq = fmaxf(fmaf(-2.0f, acc[rt][ct][r], hnv[rt][r] + hcnv[ct]), 0.0f);
                    acc[rt][ct][r] = __expf(-__builtin_amdgcn_sqrtf(sq));
                }

        // class span of this tile (block-uniform)
        const int lastc = min(cbase0 + 127, M_N - 1);
        int cLo = 0, cHi = 0;
        #pragma unroll
        for (int c = 1; c < DOUT; ++c){
            if (cbase0 >= cseg[c]) cLo = c;
            if (lastc  >= cseg[c]) cHi = c;
        }

        if (cLo == curC && cHi == curC){
            #pragma unroll
            for (int rt = 0; rt < 2; ++rt)
                #pragma unroll
                for (int r = 0; r < 4; ++r){
                    float v0 = acc[rt][0][r] + acc[rt][1][r];
                    float v1 = acc[rt][2][r] + acc[rt][3][r];
                    s[rt][r] += v0 + v1;
                }
        } else {
            if (curC >= 0) flushC(s, curC, rbase, quad, l15, accG);
            #pragma unroll
            for (int rt = 0; rt < 2; ++rt)
                #pragma unroll
                for (int r = 0; r < 4; ++r) s[rt][r] = 0.f;
            for (int c = cLo; c <= cHi; ++c){
                const int s0 = cseg[c], s1 = cseg[c+1];
                float m[2][4];
                #pragma unroll
                for (int rt = 0; rt < 2; ++rt)
                    #pragma unroll
                    for (int r = 0; r < 4; ++r){
                        float v = 0.f;
                        #pragma unroll
                        for (int ct = 0; ct < 4; ++ct){
                            int cc = cbase0 + wc*64 + ct*16 + l15;
                            v += (cc >= s0 && cc < s1) ? acc[rt][ct][r] : 0.f;
                        }
                        m[rt][r] = v;
                    }
                if (c == cHi){
                    #pragma unroll
                    for (int rt = 0; rt < 2; ++rt)
                        #pragma unroll
                        for (int r = 0; r < 4; ++r) s[rt][r] = m[rt][r];
                    curC = cHi;
                } else {
                    flushC(m, c, rbase, quad, l15, accG);
                }
            }
        }
    };

    stage(Bs0, by0);
    __syncthreads();

    #pragma unroll 1
    for (int tp = 0; tp < CTILES/2; ++tp){
        int t0 = tp*2;
        if (t0 >= nt) break;
        if (t0 + 1 < nt) stage(Bs1, by0 + t0 + 1);   // issue next-tile loads first
        compute(Bs0, by0 + t0);
        __syncthreads();                             // drains vmcnt -> Bs1 ready
        int t1 = t0 + 1;
        if (t1 >= nt) break;
        if (t1 + 1 < nt) stage(Bs0, by0 + t1 + 1);
        compute(Bs1, by0 + t1);
        __syncthreads();
    }
    if (curC >= 0) flushC(s, curC, rbase, quad, l15, accG);
}

__global__ void finalize_kernel(const float* __restrict__ accG, float* __restrict__ out){
    int b = blockIdx.x*blockDim.x + threadIdx.x;
    if (b < B_N){
        float v[DOUT]; float den = 0.f;
        #pragma unroll
        for (int c = 0; c < DOUT; ++c){ v[c] = accG[b*16 + c]; den += v[c]; }
        float inv = (den > 0.f) ? 1.0f/den : 0.f;
        #pragma unroll
        for (int c = 0; c < DOUT; ++c) out[b*DOUT + c] = logf(v[c]*inv + EPS_F);
    }
}

// ---------- launch ----------

extern "C" void kernel_launch(void* const* d_in, const int* in_sizes, int n_in,
                              void* d_out, int out_size, void* d_ws, size_t ws_size,
                              hipStream_t stream)
{
    const float* x  = (const float*)d_in[0];
    // d_in[1] = y (unused on eval path)
    const float* cx = (const float*)d_in[2];
    const int*   cy = (const int*)d_in[3];
    const float* W  = (const float*)d_in[4];
    // d_in[5] = b_enc: cancels exactly in ||h - hc||, skipped
    // d_in[6] = is_train (eval path)
    float* out = (float*)d_out;

    char* w = (char*)d_ws;
    size_t off = 0;
    bf16_t* hcb = (bf16_t*)(w + off); off += (size_t)M_PAD*DIMN*2;  // 51,216,384
    bf16_t* hb  = (bf16_t*)(w + off); off += (size_t)B_N*DIMN*2;    //    262,144
    float*  hcn = (float*) (w + off); off += (size_t)M_PAD*4;       //    800,256
    float*  hn  = (float*) (w + off); off += (size_t)B_N*4;         //      4,096
    bf16_t* Wb  = (bf16_t*)(w + off); off += (size_t)DIMN*DIN*2;    //     65,536
    size_t zoff = off;
    float* accG = (float*)(w + off); off += (size_t)B_N*16*4;       //     65,536
    int* hist     = (int*)(w + off); off += 16*DOUT*4;              // line-padded
    int* counters = (int*)(w + off); off += 16*DOUT*4;              // line-padded
    int* csg      = (int*)(w + off); off += 64;
    size_t zsize = off - zoff;

    hipMemsetAsync(w + zoff, 0, zsize, stream);
    cvt_w_kernel<<<dim3((DIMN*DIN + 255)/256), dim3(256), 0, stream>>>(W, Wb);
    hist_kernel<<<dim3(256), dim3(256), 0, stream>>>(cy, hist);
    prefix_kernel<<<dim3(1), dim3(1), 0, stream>>>(hist, csg);
    encode_kernel<<<dim3(M_PAD/128), dim3(256), 0, stream>>>(cx, Wb, hcb, hcn, M_N, cy, counters, csg);
    encode_kernel<<<dim3(B_N/128), dim3(256), 0, stream>>>(x, Wb, hb, hn, B_N, nullptr, nullptr, nullptr);
    fused_kernel<<<dim3(8, YPAD), dim3(512), 0, stream>>>(hb, hcb, hn, hcn, csg, accG);
    finalize_kernel<<<dim3((B_N + 255)/256), dim3(256), 0, stream>>>(accG, out);
}